// Round 3
// baseline (40.225 us; speedup 1.0000x reference)
//
#include <hip/hip_runtime.h>

// Problem constants (fixed by the reference)
#define NB   200    // dialogues
#define LL   50     // utterances per dialogue
#define ND   128    // feature dim
#define NROW 150    // nodes per dialogue (3 modalities * 50)

typedef __attribute__((ext_vector_type(8))) short bf16x8;  // 8 bf16 (4 VGPRs)
typedef __attribute__((ext_vector_type(4))) float f32x4;

// Per-block: one dialogue x one 32-dim quarter. LDS layout (bytes):
//   featsB : bf16 [160][136] -> 43,520 B @ 0       (GEMM B operand; rows>=150 zero)
//   Wlds   : bf16 [ 32][136] ->  8,704 B @ 43,520  (GEMM A operand, our 32 dims)
//   xbuf   : f32  [150][ 36] -> 21,600 B @ 52,224  (x state, 32 dims + pad)
// total 73,824 B  -> 2 blocks/CU
#define FS   136
#define XS4  36
#define SMEM_BYTES 73824

__device__ __forceinline__ short f2bf(float x) {          // f32 -> bf16 RTNE
    unsigned u = __float_as_uint(x);
    return (short)((u + 0x7fffu + ((u >> 16) & 1u)) >> 16);
}

__device__ __forceinline__ bf16x8 pack8(f32x4 lo, f32x4 hi) {
    bf16x8 r;
    r[0] = f2bf(lo[0]); r[1] = f2bf(lo[1]); r[2] = f2bf(lo[2]); r[3] = f2bf(lo[3]);
    r[4] = f2bf(hi[0]); r[5] = f2bf(hi[1]); r[6] = f2bf(hi[2]); r[7] = f2bf(hi[3]);
    return r;
}

__device__ __forceinline__ f32x4 upd(f32x4 x, f32x4 sc, float f) {
    // relu(x + f*(sc - 2x)),  sc = S_m + c_t
    f32x4 r;
    r[0] = fmaxf(fmaf(f, sc[0] - 2.0f * x[0], x[0]), 0.0f);
    r[1] = fmaxf(fmaf(f, sc[1] - 2.0f * x[1], x[1]), 0.0f);
    r[2] = fmaxf(fmaf(f, sc[2] - 2.0f * x[2], x[2]), 0.0f);
    r[3] = fmaxf(fmaf(f, sc[3] - 2.0f * x[3], x[3]), 0.0f);
    return r;
}

__device__ __forceinline__ f32x4 wsum(f32x4 v) {          // 64-lane butterfly all-reduce
    #pragma unroll
    for (int m = 1; m < 64; m <<= 1) {
        v[0] += __shfl_xor(v[0], m, 64);
        v[1] += __shfl_xor(v[1], m, 64);
        v[2] += __shfl_xor(v[2], m, 64);
        v[3] += __shfl_xor(v[3], m, 64);
    }
    return v;
}

__launch_bounds__(512, 4)
__global__ void hgcn_fused(const float* __restrict__ a,
                           const float* __restrict__ v,
                           const float* __restrict__ l,
                           const float* __restrict__ qmask,
                           const float* __restrict__ W1,
                           const float* __restrict__ b1,
                           const float* __restrict__ se,
                           const float* __restrict__ kap,
                           float* __restrict__ out) {
    extern __shared__ char smem[];
    short* featsB = (short*)smem;                 // [160][FS]
    short* Wlds   = (short*)(smem + 43520);       // [32][FS]
    float* xbuf   = (float*)(smem + 52224);       // [150][XS4]

    // XCD-aware mapping: the 4 dim-quarter blocks of a dialogue land on the
    // same XCD (bid%8 assumed round-robin) -> feats re-reads hit that L2.
    const int bid  = blockIdx.x;
    const int slot = bid >> 3;                    // 0..99
    const int b    = (bid & 7) * 25 + (slot >> 2);
    const int q    = slot & 3;                    // dim-quarter (dims 32q..32q+31)
    const int tid  = threadIdx.x;
    const int lane = tid & 63;
    const int w    = tid >> 6;                    // wave 0..7

    const f32x4* a4  = (const f32x4*)a;
    const f32x4* v4  = (const f32x4*)v;
    const f32x4* l4  = (const f32x4*)l;
    const f32x4* se4 = (const f32x4*)se;
    const f32x4* W14 = (const f32x4*)W1;
    f32x4* out4 = (f32x4*)out;

    // ---- Phase 1: stage feats (bf16, all 128 k-dims) + write feats-output
    //      for our dim quarter (removes the epilogue global re-read).
    for (int i = tid; i < 2560; i += 512) {
        int row = i >> 4, c8 = i & 15;            // c8 = 8-float chunk
        f32x4 f0 = {0.f, 0.f, 0.f, 0.f}, f1 = {0.f, 0.f, 0.f, 0.f};
        if (row < NROW) {
            int m = row >= 100 ? 2 : (row >= 50 ? 1 : 0);
            int t = row - m * 50;
            const f32x4* src = (m == 0) ? l4 : ((m == 1) ? a4 : v4);
            int base = (b * LL + t) * 32 + c8 * 2;
            f0 = src[base]; f1 = src[base + 1];
            if (m == 0) {
                int qb  = (t * NB + b) * 2;
                int spk = qmask[qb + 1] > qmask[qb] ? 1 : 0;
                f0 += se4[spk * 32 + c8 * 2];
                f1 += se4[spk * 32 + c8 * 2 + 1];
            }
            if ((c8 >> 2) == q) {                 // our 32 dims -> feats half of out
                size_t o = (size_t)(b * LL + t) * 192 + m * 64 + c8 * 2;
                out4[o]     = f0;
                out4[o + 1] = f1;
            }
        }
        *(bf16x8*)&featsB[row * FS + c8 * 8] = pack8(f0, f1);
    }
    // ---- Phase 2: stage our 32 rows of W1 (bf16) --------------------------
    {
        int row = tid >> 4, c8 = tid & 15;        // 512 items, one per thread
        f32x4 f0 = W14[(32 * q + row) * 32 + c8 * 2];
        f32x4 f1 = W14[(32 * q + row) * 32 + c8 * 2 + 1];
        *(bf16x8*)&Wlds[row * FS + c8 * 8] = pack8(f0, f1);
    }
    __syncthreads();

    // ---- Phase 3: MFMA GEMM  x[n][d] for d in our quarter -----------------
    // wave w: dt = w&1 (16-dim tile), ng = w>>1 (node groups, nt += 4)
    {
        const int dt = w & 1;
        const int ng = w >> 1;
        const int r  = lane & 15;
        const int qf = lane >> 4;
        bf16x8 afr[4];
        #pragma unroll
        for (int ks = 0; ks < 4; ++ks)
            afr[ks] = *(const bf16x8*)&Wlds[(16 * dt + r) * FS + ks * 32 + qf * 8];
        f32x4 bias = *(const f32x4*)&b1[32 * q + 16 * dt + 4 * qf];
        for (int nt = ng; nt < 10; nt += 4) {
            f32x4 acc = {0.f, 0.f, 0.f, 0.f};
            #pragma unroll
            for (int ks = 0; ks < 4; ++ks) {
                bf16x8 bfr = *(const bf16x8*)&featsB[(16 * nt + r) * FS + ks * 32 + qf * 8];
                acc = __builtin_amdgcn_mfma_f32_16x16x32_bf16(afr[ks], bfr, acc, 0, 0, 0);
            }
            int node = 16 * nt + r;               // D: lane holds x[node][16dt+4qf+e]
            if (node < NROW)
                *(f32x4*)&xbuf[node * XS4 + 16 * dt + 4 * qf] = acc + bias;
        }
    }
    __syncthreads();

    // ---- Phase 4: register-resident HGCN iterations -----------------------
    // thread (wave=d4, lane=t) owns x[m*50+t][4*d4..4*d4+3] for m=0,1,2.
    const int t  = lane;
    const int d4 = w;
    const f32x4 z = {0.f, 0.f, 0.f, 0.f};
    f32x4 x0 = z, x1 = z, x2 = z;
    if (t < LL) {
        x0 = *(const f32x4*)&xbuf[t         * XS4 + 4 * d4];
        x1 = *(const f32x4*)&xbuf[(50 + t)  * XS4 + 4 * d4];
        x2 = *(const f32x4*)&xbuf[(100 + t) * XS4 + 4 * d4];
    }
    const float inv = 1.0f / 51.0f;
    #pragma unroll
    for (int it = 0; it < 4; ++it) {
        const float f = kap[it] * inv;
        f32x4 c  = x0 + x1 + x2;                  // cross-modal sum (in-register)
        f32x4 s0 = wsum(x0);                      // block sums via butterfly
        f32x4 s1 = wsum(x1);
        f32x4 s2 = wsum(x2);
        x0 = upd(x0, s0 + c, f);
        x1 = upd(x1, s1 + c, f);
        x2 = upd(x2, s2 + c, f);
        if (t >= LL) { x0 = z; x1 = z; x2 = z; }  // keep inactive lanes inert
    }
    if (t < LL) {
        *(f32x4*)&xbuf[t         * XS4 + 4 * d4] = x0;
        *(f32x4*)&xbuf[(50 + t)  * XS4 + 4 * d4] = x1;
        *(f32x4*)&xbuf[(100 + t) * XS4 + 4 * d4] = x2;
    }
    __syncthreads();

    // ---- Phase 5: x half of output, coalesced (128B chunks per (t,m)) -----
    for (int i = tid; i < 1200; i += 512) {
        int tt  = i / 24;
        int rem = i - tt * 24;
        int m   = rem >> 3, dd = rem & 7;
        f32x4 val = *(const f32x4*)&xbuf[(m * 50 + tt) * XS4 + 4 * dd];
        out4[(size_t)(b * LL + tt) * 192 + m * 64 + 32 + q * 8 + dd] = val;
    }
}

extern "C" void kernel_launch(void* const* d_in, const int* in_sizes, int n_in,
                              void* d_out, int out_size, void* d_ws, size_t ws_size,
                              hipStream_t stream) {
    const float* a     = (const float*)d_in[0];
    const float* v     = (const float*)d_in[1];
    const float* l     = (const float*)d_in[2];
    const float* qmask = (const float*)d_in[3];
    const float* W1    = (const float*)d_in[4];
    const float* b1    = (const float*)d_in[5];
    const float* se    = (const float*)d_in[6];
    const float* kap   = (const float*)d_in[7];
    // d_in[8] = edge_index (closed-form structure; unused), d_in[9] = epoch (unused)
    float* out = (float*)d_out;

    hipFuncSetAttribute((const void*)hgcn_fused,
                        hipFuncAttributeMaxDynamicSharedMemorySize, SMEM_BYTES);
    hgcn_fused<<<800, 512, SMEM_BYTES, stream>>>(a, v, l, qmask, W1, b1, se, kap, out);
}